// Round 6
// baseline (2375.264 us; speedup 1.0000x reference)
//
#include <hip/hip_runtime.h>
#include <math.h>

#define BB 8
#define NN 1000
#define CC 81
#define NC 80                     // foreground classes
#define IMG_W_M1 1332.0f
#define IMG_H_M1 799.0f
#define SCORE_THRESH 0.05f
#define NMS_THRESH 0.5f
#define DETS 100
#define DW_CLIP 4.135166556742356f  // log(1000/16) rounded to f32
#define NBINS 2048
#define SELCAP 1024
#define CAPI 80000                // per-image survivor cap == 80*1000 absolute max
#define NWAVE 16

// ws layout (bytes):
//   [0,        5120000)   cand  float2[8][CAPI] = {score, bitcast(flatidx)}
//   [5242880,  5767168)   slow-path scratch, 65536 B per image (never taken)

__global__ __launch_bounds__(1024) void fused_post(
    const float* __restrict__ logits, const float* __restrict__ reg,
    const float* __restrict__ props, float* __restrict__ ws_cand,
    float* __restrict__ ws_slow, float* __restrict__ dets_out,
    float* __restrict__ labels_out) {
#pragma clang fp contract(off)
  __shared__ float m_row[NN];
  __shared__ float s_row[NN];
  __shared__ float w_s[NWAVE][64];
  __shared__ int   w_i[NWAVE][64];
  __shared__ unsigned hist[NBINS];
  __shared__ float sel_s[SELCAP];
  __shared__ int   sel_f[SELCAP];
  __shared__ int s_q[NC];
  __shared__ int s_nc, s_qn, s_m, s_cut, s_c2;

  const int img = blockIdx.x;
  const int t = threadIdx.x;
  const int wave = t >> 6;
  const int lane = t & 63;

  if (t == 0) { s_nc = 0; s_qn = 0; s_m = 0; s_cut = NBINS; }
  for (int b = t; b < NBINS; b += 1024) hist[b] = 0u;

  // ---- Phase A: per-row softmax stats (identical op order to reference) ----
  for (int r = t; r < NN; r += 1024) {
    const float* l = logits + (size_t)(img * NN + r) * CC;
    float m = l[0];
    for (int c = 1; c < CC; ++c) m = fmaxf(m, l[c]);
    float s = 0.0f;
    for (int c = 0; c < CC; ++c) s += expf(l[c] - m);
    m_row[r] = m;
    s_row[r] = s;
  }
  __syncthreads();

  float2* cand = (float2*)ws_cand + (size_t)img * CAPI;

  // ---- Phase B: one wave per class; fast path n<=64, zero barriers ----
  for (int cm1 = wave; cm1 < NC; cm1 += NWAVE) {
    const int cls = cm1 + 1;
    // ballot-compaction of rows with prob > thresh
    int n = 0;
    for (int k = 0; k < 16; ++k) {
      int r = k * 64 + lane;
      bool pred = false;
      float p = 0.0f;
      if (r < NN) {
        float lc = logits[(size_t)(img * NN + r) * CC + cls];
        p = expf(lc - m_row[r]) / s_row[r];    // == verified pT formula
        pred = p > SCORE_THRESH;
      }
      unsigned long long mb = __ballot(pred);
      if (pred) {
        int pos = n + (int)__popcll(mb & ((1ull << lane) - 1ull));
        if (pos < 64) { w_s[wave][pos] = p; w_i[wave][pos] = r; }
      }
      n += (int)__popcll(mb);
    }
    if (n == 0) continue;
    if (n > 64) {                 // queue for block-wide slow path
      if (lane == 0) { int q = atomicAdd(&s_qn, 1); s_q[q] = cm1; }
      continue;
    }
    // shfl rank-sort by (score desc, row asc) == stable argsort(-scores)
    bool own = lane < n;
    float sv = own ? w_s[wave][lane] : -1.0f;
    int   iv = own ? w_i[wave][lane] : 0x7fffffff;
    int rank = 0;
    for (int j = 0; j < n; ++j) {
      float sj = __shfl(sv, j);
      int   ij = __shfl(iv, j);
      rank += (int)((sj > sv) | ((sj == sv) & (ij < iv)));
    }
    if (own) { w_s[wave][rank] = sv; w_i[wave][rank] = iv; }
    float ss  = own ? w_s[wave][lane] : 0.0f;   // lane = sorted position
    int  sidx = own ? w_i[wave][lane] : 0;
    // decode + clip (BoxCoder.decode, TO_REMOVE=1) — verified bit-exact
    float bx1 = 0.f, by1 = 0.f, bx2 = 0.f, by2 = 0.f;
    if (own) {
      int row = img * NN + sidx;
      float4 pr = ((const float4*)props)[row];
      float w = pr.z - pr.x + 1.0f, h = pr.w - pr.y + 1.0f;
      float cx = pr.x + 0.5f * w,  cy = pr.y + 0.5f * h;
      float4 rv = *(const float4*)(reg + (size_t)row * (CC * 4) + cls * 4);
      float dx = rv.x / 10.0f, dy = rv.y / 10.0f;
      float dw = fminf(rv.z / 5.0f, DW_CLIP);
      float dh = fminf(rv.w / 5.0f, DW_CLIP);
      float pcx = dx * w + cx, pcy = dy * h + cy;
      float pw = expf(dw) * w, ph = expf(dh) * h;
      bx1 = fminf(fmaxf(pcx - 0.5f * pw, 0.0f), IMG_W_M1);
      by1 = fminf(fmaxf(pcy - 0.5f * ph, 0.0f), IMG_H_M1);
      bx2 = fminf(fmaxf(pcx + 0.5f * pw - 1.0f, 0.0f), IMG_W_M1);
      by2 = fminf(fmaxf(pcy + 0.5f * ph - 1.0f, 0.0f), IMG_H_M1);
    }
    // ballot greedy NMS (verified vs reference semantics)
    float areaSelf = (bx2 - bx1) * (by2 - by1);
    unsigned long long rem = __ballot(own);
    unsigned long long kept = 0ull;
    while (rem) {
      int i = __builtin_ctzll(rem);
      kept |= 1ull << i;
      rem &= ~(1ull << i);
      float cx1 = __shfl(bx1, i), cy1 = __shfl(by1, i);
      float cx2 = __shfl(bx2, i), cy2 = __shfl(by2, i);
      float areaB = (cx2 - cx1) * (cy2 - cy1);
      float wx = fmaxf(fminf(bx2, cx2) - fmaxf(bx1, cx1), 0.0f);
      float wy = fmaxf(fminf(by2, cy2) - fmaxf(by1, cy1), 0.0f);
      float inter = wx * wy;
      float iou = inter / ((areaSelf + areaB) - inter + 1e-9f);
      rem &= ~__ballot(iou > NMS_THRESH);
    }
    int tot = (int)__popcll(kept);
    int base = 0;
    if (lane == 0) base = atomicAdd(&s_nc, tot);
    base = __shfl(base, 0);
    if (own && ((kept >> lane) & 1ull)) {
      int pos = base + (int)__popcll(kept & ((1ull << lane) - 1ull));
      float2 v;
      v.x = ss;
      v.y = __int_as_float(cm1 * NN + sidx);
      cand[pos] = v;
    }
  }
  __syncthreads();

  // ---- Phase C: slow path for n>64 classes (never taken; correctness only) ----
  float* gb = ws_slow + (size_t)img * 16384;     // 65536 B per image
  float* g_sc  = gb;            int* g_idx  = (int*)(gb + 1000);
  float* g_ssc = gb + 2000;     int* g_sidx = (int*)(gb + 3000);
  float* g_box = gb + 4000;     int* g_keep = (int*)(gb + 8000);
  for (int qi = 0; qi < s_qn; ++qi) {
    int cm1 = s_q[qi], cls = cm1 + 1;
    if (t == 0) s_c2 = 0;
    __syncthreads();
    for (int r = t; r < NN; r += 1024) {
      float lc = logits[(size_t)(img * NN + r) * CC + cls];
      float p = expf(lc - m_row[r]) / s_row[r];
      if (p > SCORE_THRESH) { int pos = atomicAdd(&s_c2, 1); g_sc[pos] = p; g_idx[pos] = r; }
    }
    __threadfence(); __syncthreads();
    int n = s_c2;
    for (int i = t; i < n; i += 1024) {
      float si = g_sc[i]; int ii = g_idx[i]; int rank = 0;
      for (int j = 0; j < n; ++j) {
        float sj = g_sc[j];
        rank += (int)((sj > si) | ((sj == si) & (g_idx[j] < ii)));
      }
      g_ssc[rank] = si; g_sidx[rank] = ii;
    }
    __threadfence(); __syncthreads();
    for (int i = t; i < n; i += 1024) {
      int row = img * NN + g_sidx[i];
      float4 pr = ((const float4*)props)[row];
      float w = pr.z - pr.x + 1.0f, h = pr.w - pr.y + 1.0f;
      float cx = pr.x + 0.5f * w,  cy = pr.y + 0.5f * h;
      float4 rv = *(const float4*)(reg + (size_t)row * (CC * 4) + cls * 4);
      float dx = rv.x / 10.0f, dy = rv.y / 10.0f;
      float dw = fminf(rv.z / 5.0f, DW_CLIP);
      float dh = fminf(rv.w / 5.0f, DW_CLIP);
      float pcx = dx * w + cx, pcy = dy * h + cy;
      float pw = expf(dw) * w, ph = expf(dh) * h;
      g_box[i * 4 + 0] = fminf(fmaxf(pcx - 0.5f * pw, 0.0f), IMG_W_M1);
      g_box[i * 4 + 1] = fminf(fmaxf(pcy - 0.5f * ph, 0.0f), IMG_H_M1);
      g_box[i * 4 + 2] = fminf(fmaxf(pcx + 0.5f * pw - 1.0f, 0.0f), IMG_W_M1);
      g_box[i * 4 + 3] = fminf(fmaxf(pcy + 0.5f * ph - 1.0f, 0.0f), IMG_H_M1);
      g_keep[i] = 1;
    }
    __threadfence(); __syncthreads();
    for (int i = 0; i < n; ++i) {
      if (g_keep[i]) {
        float ax1 = g_box[i*4], ay1 = g_box[i*4+1], ax2 = g_box[i*4+2], ay2 = g_box[i*4+3];
        float areaA = (ax2 - ax1) * (ay2 - ay1);
        for (int j = i + 1 + t; j < n; j += 1024) {
          if (!g_keep[j]) continue;
          float bx1 = g_box[j*4], by1 = g_box[j*4+1], bx2 = g_box[j*4+2], by2 = g_box[j*4+3];
          float areaB = (bx2 - bx1) * (by2 - by1);
          float wx = fmaxf(fminf(ax2, bx2) - fmaxf(ax1, bx1), 0.0f);
          float wy = fmaxf(fminf(ay2, by2) - fmaxf(ay1, by1), 0.0f);
          float inter = wx * wy;
          if (inter / ((areaA + areaB) - inter + 1e-9f) > NMS_THRESH) g_keep[j] = 0;
        }
      }
      __threadfence(); __syncthreads();
    }
    if (t == 0) {
      int tot = 0;
      for (int j = 0; j < n; ++j) tot += g_keep[j] ? 1 : 0;
      s_c2 = (tot > 0) ? atomicAdd(&s_nc, tot) : 0;
    }
    __syncthreads();
    for (int i = t; i < n; i += 1024) {
      if (g_keep[i]) {
        int pos = 0;
        for (int j = 0; j < i; ++j) pos += g_keep[j] ? 1 : 0;
        float2 v; v.x = g_ssc[i]; v.y = __int_as_float(cm1 * NN + g_sidx[i]);
        cand[s_c2 + pos] = v;
      }
    }
    __syncthreads();
  }
  __threadfence();   // drain cand stores to L2; L1 has no stale lines (write-through)
  __syncthreads();

  // ---- Phase D: per-image top-K via histogram cut + exact rank ----
  const int n_all = s_nc;
  const int K = (n_all < DETS) ? n_all : DETS;   // all cand scores > 0.05 > 0

  for (int i = t; i < n_all; i += 1024) {
    float sc = cand[i].x;
    int bin = (int)(sc * (float)NBINS);
    if (bin > NBINS - 1) bin = NBINS - 1;
    atomicAdd(&hist[bin], 1u);
  }
  __syncthreads();

  // wave 0: cut = largest bin with count(bin >= cut) >= K (superbin = 32 bins)
  if (t < 64 && K > 0) {
    unsigned s = 0;
    for (int b = 0; b < 32; ++b) s += hist[t * 32 + b];
    unsigned suf = s;
    for (int d = 1; d < 64; d <<= 1) {
      unsigned o = __shfl_down(suf, d);
      if (t + d < 64) suf += o;
    }
    unsigned long long m1 = __ballot(suf >= (unsigned)K);
    int S = 63 - __builtin_clzll(m1);
    unsigned tail = 0;
    if (S < 63) tail = __shfl(suf, S + 1);
    unsigned h2 = (t < 32) ? hist[S * 32 + t] : 0u;
    unsigned suf2 = h2;
    for (int d = 1; d < 64; d <<= 1) {
      unsigned o = __shfl_down(suf2, d);
      if (t + d < 64) suf2 += o;
    }
    unsigned long long m2 = __ballot((suf2 + tail) >= (unsigned)K);
    int Ls = 63 - __builtin_clzll(m2);
    if (t == 0) s_cut = S * 32 + Ls;
  }
  __syncthreads();
  const int cut = s_cut;

  // prefill ranks >= K (reference: topv==0 -> box 0, score 0, label -1)
  for (int k = t; k < DETS; k += 1024) {
    if (k >= K) {
      float* d = dets_out + (size_t)(img * DETS + k) * 5;
      d[0] = 0.0f; d[1] = 0.0f; d[2] = 0.0f; d[3] = 0.0f; d[4] = 0.0f;
      labels_out[img * DETS + k] = -1.0f;
    }
  }

  // select bin >= cut: upward-closed => in-set rank == global rank
  for (int i = t; i < n_all; i += 1024) {
    float sc = cand[i].x;
    int bin = (int)(sc * (float)NBINS);
    if (bin > NBINS - 1) bin = NBINS - 1;
    if (bin >= cut) {
      int p = atomicAdd(&s_m, 1);
      if (p < SELCAP) { sel_s[p] = sc; sel_f[p] = __float_as_int(cand[i].y); }
    }
  }
  __syncthreads();
  const int m = s_m;

  if (m <= SELCAP) {
    for (int i = t; i < m; i += 1024) {
      float si = sel_s[i];
      int   fi = sel_f[i];
      int rank = 0;
      for (int j = 0; j < m; ++j) {
        float sj = sel_s[j];
        rank += (int)((sj > si) | ((sj == si) & (sel_f[j] < fi)));
      }
      if (rank < DETS) {
        int cm1 = fi / NN;
        int row = img * NN + (fi - cm1 * NN);
        float4 pr = ((const float4*)props)[row];
        float w = pr.z - pr.x + 1.0f, h = pr.w - pr.y + 1.0f;
        float cx = pr.x + 0.5f * w,  cy = pr.y + 0.5f * h;
        float4 rv = *(const float4*)(reg + (size_t)row * (CC * 4) + (cm1 + 1) * 4);
        float dx = rv.x / 10.0f, dy = rv.y / 10.0f;
        float dw = fminf(rv.z / 5.0f, DW_CLIP);
        float dh = fminf(rv.w / 5.0f, DW_CLIP);
        float pcx = dx * w + cx, pcy = dy * h + cy;
        float pw = expf(dw) * w, ph = expf(dh) * h;
        float* d = dets_out + (size_t)(img * DETS + rank) * 5;
        d[0] = fminf(fmaxf(pcx - 0.5f * pw, 0.0f), IMG_W_M1);
        d[1] = fminf(fmaxf(pcy - 0.5f * ph, 0.0f), IMG_H_M1);
        d[2] = fminf(fmaxf(pcx + 0.5f * pw - 1.0f, 0.0f), IMG_W_M1);
        d[3] = fminf(fmaxf(pcy + 0.5f * ph - 1.0f, 0.0f), IMG_H_M1);
        d[4] = si;
        labels_out[img * DETS + rank] = (float)(cm1 + 1);
      }
    }
  } else {
    // mass-tie fallback: exact O(n^2) rank over global cand (never taken)
    for (int i = t; i < n_all; i += 1024) {
      float si = cand[i].x;
      int   fi = __float_as_int(cand[i].y);
      int rank = 0;
      for (int j = 0; j < n_all; ++j) {
        float sj = cand[j].x;
        int   fj = __float_as_int(cand[j].y);
        rank += (int)((sj > si) | ((sj == si) & (fj < fi)));
      }
      if (rank < DETS) {
        int cm1 = fi / NN;
        int row = img * NN + (fi - cm1 * NN);
        float4 pr = ((const float4*)props)[row];
        float w = pr.z - pr.x + 1.0f, h = pr.w - pr.y + 1.0f;
        float cx = pr.x + 0.5f * w,  cy = pr.y + 0.5f * h;
        float4 rv = *(const float4*)(reg + (size_t)row * (CC * 4) + (cm1 + 1) * 4);
        float dx = rv.x / 10.0f, dy = rv.y / 10.0f;
        float dw = fminf(rv.z / 5.0f, DW_CLIP);
        float dh = fminf(rv.w / 5.0f, DW_CLIP);
        float pcx = dx * w + cx, pcy = dy * h + cy;
        float pw = expf(dw) * w, ph = expf(dh) * h;
        float* d = dets_out + (size_t)(img * DETS + rank) * 5;
        d[0] = fminf(fmaxf(pcx - 0.5f * pw, 0.0f), IMG_W_M1);
        d[1] = fminf(fmaxf(pcy - 0.5f * ph, 0.0f), IMG_H_M1);
        d[2] = fminf(fmaxf(pcx + 0.5f * pw - 1.0f, 0.0f), IMG_W_M1);
        d[3] = fminf(fmaxf(pcy + 0.5f * ph - 1.0f, 0.0f), IMG_H_M1);
        d[4] = si;
        labels_out[img * DETS + rank] = (float)(cm1 + 1);
      }
    }
  }
}

extern "C" void kernel_launch(void* const* d_in, const int* in_sizes, int n_in,
                              void* d_out, int out_size, void* d_ws, size_t ws_size,
                              hipStream_t stream) {
  const float* logits = (const float*)d_in[0];   // [8000, 81]
  const float* reg    = (const float*)d_in[1];   // [8000, 324]
  const float* props  = (const float*)d_in[2];   // [8000, 4]
  // d_in[3] = features, unused (OUTPUT_FEATURE=False)

  float* out = (float*)d_out;                    // dets [8,100,5] then labels [8,100]
  char* ws = (char*)d_ws;
  float* ws_cand = (float*)(ws);
  float* ws_slow = (float*)(ws + 5242880);

  fused_post<<<BB, 1024, 0, stream>>>(logits, reg, props, ws_cand, ws_slow,
                                      out, out + BB * DETS * 5);
}

// Round 7
// 301.742 us; speedup vs baseline: 7.8718x; 7.8718x over previous
//
#include <hip/hip_runtime.h>
#include <math.h>

#define BB 8
#define NN 1000
#define CC 81
#define NC 80                     // foreground classes
#define IMG_W_M1 1332.0f
#define IMG_H_M1 799.0f
#define SCORE_THRESH 0.05f
#define NMS_THRESH 0.5f
#define DETS 100
#define DW_CLIP 4.135166556742356f  // log(1000/16) rounded to f32
#define NBINS 4096
#define SELCAP 1024
#define CAPI 80000                // per-image survivor cap = 80*1000 absolute max
#define POISON 0xAAAAAAAAu       // harness re-poisons ws to 0xAA every launch

// ws layout (bytes):
//   [0,        5120000)  cand u64[8][CAPI] = {hi: flatidx, lo: score bits}
//   [5120000,  5120032)  counters u32[8]   (survivor count per image)
//   [5120064,  5120096)  done     u32[8]   (finished-block count per image)

__device__ __forceinline__ void emit_cand(unsigned long long* cand, int img,
                                          int pos, float sc, int fl) {
  if (pos >= 0 && pos < CAPI) {
    unsigned long long v = ((unsigned long long)(unsigned)fl << 32) |
                           (unsigned long long)__float_as_uint(sc);
    // agent-scope atomic store: coherent across XCDs without relying on fences
    __hip_atomic_store(&cand[(size_t)img * CAPI + pos], v,
                       __ATOMIC_RELAXED, __HIP_MEMORY_SCOPE_AGENT);
  }
}

__global__ __launch_bounds__(256) void fused_post(
    const float* __restrict__ logits, const float* __restrict__ reg,
    const float* __restrict__ props, unsigned long long* __restrict__ cand,
    unsigned* __restrict__ counters, unsigned* __restrict__ done,
    float* __restrict__ dets_out, float* __restrict__ labels_out) {
#pragma clang fp contract(off)
  __shared__ float m_row[NN];
  __shared__ float s_row[NN];
  __shared__ union {
    struct {
      float score[NN]; int idx[NN];
      float sscore[NN]; int sidx[NN];
      float box[NN * 4];
      unsigned char keep[NN];
    } nms;                                   // ~33 KB
    struct {
      unsigned hist[NBINS];                  // 16 KB
      float sel_s[SELCAP]; int sel_f[SELCAP];
    } tk;                                    // 24 KB
  } u;
  __shared__ int s_cnt;
  __shared__ unsigned s_base;
  __shared__ int s_last, s_n2, s_m, s_cut;

  const int img = blockIdx.x / NC;
  const int cm1 = blockIdx.x % NC;
  const int cls = cm1 + 1;
  const int t = threadIdx.x;

  if (t == 0) {
    // first toucher flips poison -> 0; losers no-op (atomics totally ordered)
    atomicCAS(&counters[img], POISON, 0u);
    atomicCAS(&done[img], POISON, 0u);
    s_cnt = 0;
  }

  // ---- Stats: per-row softmax max/sum (verbatim verified formula) ----
  // Redundant per block (80x/image) but cheap at 640-block parallelism;
  // second pass over the row is L1-hot.
  for (int r = t; r < NN; r += 256) {
    const float* l = logits + (size_t)(img * NN + r) * CC;
    float m = l[0];
    for (int c = 1; c < CC; ++c) m = fmaxf(m, l[c]);
    float s = 0.0f;
    for (int c = 0; c < CC; ++c) s += expf(l[c] - m);
    m_row[r] = m;
    s_row[r] = s;
  }
  __syncthreads();   // also orders t0's CAS before any append below

  // ---- Phase 1: threshold + compact (prob formula verified in R6) ----
  for (int r = t; r < NN; r += 256) {
    float lc = logits[(size_t)(img * NN + r) * CC + cls];
    float p = expf(lc - m_row[r]) / s_row[r];
    if (p > SCORE_THRESH) {
      int pos = atomicAdd(&s_cnt, 1);
      u.nms.score[pos] = p;
      u.nms.idx[pos] = r;
    }
  }
  __syncthreads();
  const int n = s_cnt;

  // ---- Phase 2: rank sort by (score desc, row asc) == stable argsort ----
  for (int i = t; i < n; i += 256) {
    float si = u.nms.score[i];
    int   ii = u.nms.idx[i];
    int rank = 0;
    for (int j = 0; j < n; ++j) {
      float sj = u.nms.score[j];
      rank += (int)((sj > si) | ((sj == si) & (u.nms.idx[j] < ii)));
    }
    u.nms.sscore[rank] = si;
    u.nms.sidx[rank] = ii;
  }
  __syncthreads();

  // ---- Phase 3: decode + clip (BoxCoder.decode, TO_REMOVE=1; verbatim) ----
  for (int i = t; i < n; i += 256) {
    int r = u.nms.sidx[i];
    int row = img * NN + r;
    float x1 = props[row * 4 + 0], y1 = props[row * 4 + 1];
    float x2 = props[row * 4 + 2], y2 = props[row * 4 + 3];
    float w = x2 - x1 + 1.0f, h = y2 - y1 + 1.0f;
    float cx = x1 + 0.5f * w,  cy = y1 + 0.5f * h;
    const float* rg = reg + (size_t)row * (CC * 4) + cls * 4;
    float dx = rg[0] / 10.0f, dy = rg[1] / 10.0f;
    float dw = fminf(rg[2] / 5.0f, DW_CLIP);
    float dh = fminf(rg[3] / 5.0f, DW_CLIP);
    float pcx = dx * w + cx, pcy = dy * h + cy;
    float pw = expf(dw) * w, ph = expf(dh) * h;
    float bx1 = fminf(fmaxf(pcx - 0.5f * pw, 0.0f), IMG_W_M1);
    float by1 = fminf(fmaxf(pcy - 0.5f * ph, 0.0f), IMG_H_M1);
    float bx2 = fminf(fmaxf(pcx + 0.5f * pw - 1.0f, 0.0f), IMG_W_M1);
    float by2 = fminf(fmaxf(pcy + 0.5f * ph - 1.0f, 0.0f), IMG_H_M1);
    u.nms.box[i * 4 + 0] = bx1;
    u.nms.box[i * 4 + 1] = by1;
    u.nms.box[i * 4 + 2] = bx2;
    u.nms.box[i * 4 + 3] = by2;
    u.nms.keep[i] = 1;
  }
  __syncthreads();

  // ---- Phase 4+5: greedy NMS + emit survivors (verified R5 logic) ----
  if (n <= 64) {
    if (t < 64) {
      bool own = t < n;
      float bx1 = 0.f, by1 = 0.f, bx2 = 0.f, by2 = 0.f;
      if (own) {
        bx1 = u.nms.box[t * 4 + 0]; by1 = u.nms.box[t * 4 + 1];
        bx2 = u.nms.box[t * 4 + 2]; by2 = u.nms.box[t * 4 + 3];
      }
      float areaSelf = (bx2 - bx1) * (by2 - by1);
      unsigned long long rem = __ballot(own);
      unsigned long long kept = 0ull;
      while (rem) {
        int i = __builtin_ctzll(rem);
        kept |= 1ull << i;
        rem &= ~(1ull << i);
        float cx1 = __shfl(bx1, i), cy1 = __shfl(by1, i);
        float cx2 = __shfl(bx2, i), cy2 = __shfl(by2, i);
        float areaB = (cx2 - cx1) * (cy2 - cy1);
        float wx = fmaxf(fminf(bx2, cx2) - fmaxf(bx1, cx1), 0.0f);
        float wy = fmaxf(fminf(by2, cy2) - fmaxf(by1, cy1), 0.0f);
        float inter = wx * wy;
        float iou = inter / ((areaSelf + areaB) - inter + 1e-9f);
        rem &= ~__ballot(iou > NMS_THRESH);
      }
      int tot = (int)__popcll(kept);
      unsigned base = 0u;
      if (t == 0 && tot > 0) base = atomicAdd(&counters[img], (unsigned)tot);
      base = __shfl(base, 0);
      if (own && ((kept >> t) & 1ull)) {
        int pos = (int)base + (int)__popcll(kept & ((1ull << t) - 1ull));
        emit_cand(cand, img, pos, u.nms.sscore[t], cm1 * NN + u.nms.sidx[t]);
      }
    }
  } else {
    // Generic fallback (n>64): barriered LDS loop, identical semantics.
    for (int i = 0; i < n; ++i) {
      if (u.nms.keep[i]) {
        float ax1 = u.nms.box[i*4], ay1 = u.nms.box[i*4+1];
        float ax2 = u.nms.box[i*4+2], ay2 = u.nms.box[i*4+3];
        float areaA = (ax2 - ax1) * (ay2 - ay1);
        for (int j = i + 1 + t; j < n; j += 256) {
          if (!u.nms.keep[j]) continue;
          float bx1 = u.nms.box[j*4], by1 = u.nms.box[j*4+1];
          float bx2 = u.nms.box[j*4+2], by2 = u.nms.box[j*4+3];
          float areaB = (bx2 - bx1) * (by2 - by1);
          float wx = fmaxf(fminf(ax2, bx2) - fmaxf(ax1, bx1), 0.0f);
          float wy = fmaxf(fminf(ay2, by2) - fmaxf(ay1, by1), 0.0f);
          float inter = wx * wy;
          if (inter / ((areaA + areaB) - inter + 1e-9f) > NMS_THRESH)
            u.nms.keep[j] = 0;
        }
      }
      __syncthreads();
    }
    if (t == 0) {
      int tot = 0;
      for (int j = 0; j < n; ++j) tot += (int)u.nms.keep[j];
      s_base = (tot > 0) ? atomicAdd(&counters[img], (unsigned)tot) : 0u;
    }
    __syncthreads();
    for (int i = t; i < n; i += 256) {
      if (u.nms.keep[i]) {
        int pos = 0;
        for (int j = 0; j < i; ++j) pos += (int)u.nms.keep[j];
        emit_cand(cand, img, (int)s_base + pos,
                  u.nms.sscore[i], cm1 * NN + u.nms.sidx[i]);
      }
    }
  }

  // ---- Signal done; last block of the image runs topk ----
  __threadfence();        // every thread: order its stores before the signal
  __syncthreads();
  if (t == 0) {
    unsigned old = __hip_atomic_fetch_add(&done[img], 1u,
                                          __ATOMIC_ACQ_REL,
                                          __HIP_MEMORY_SCOPE_AGENT);
    s_last = (old == NC - 1) ? 1 : 0;
  }
  __syncthreads();
  if (!s_last) return;

  __threadfence();        // acquire side: invalidate L1 before reading cand
  if (t == 0) {
    s_n2 = (int)__hip_atomic_load(&counters[img], __ATOMIC_ACQUIRE,
                                  __HIP_MEMORY_SCOPE_AGENT);
    s_m = 0; s_cut = NBINS;
  }
  __syncthreads();        // all threads past u.nms; s_n2 published
  for (int b = t; b < NBINS; b += 256) u.tk.hist[b] = 0u;
  __syncthreads();

  int n2 = s_n2;
  if (n2 > CAPI) n2 = CAPI;
  const int K = (n2 < DETS) ? n2 : DETS;   // all survivor scores > 0.05 > 0
  const unsigned long long* cb = cand + (size_t)img * CAPI;

  // Histogram. bin = floor(sc*4096) monotone => {bin>=cut} upward-closed.
  for (int i = t; i < n2; i += 256) {
    unsigned long long v = __hip_atomic_load(&cb[i], __ATOMIC_RELAXED,
                                             __HIP_MEMORY_SCOPE_AGENT);
    float sc = __uint_as_float((unsigned)v);
    int bin = (int)(sc * (float)NBINS);
    if (bin > NBINS - 1) bin = NBINS - 1;
    atomicAdd(&u.tk.hist[bin], 1u);
  }
  __syncthreads();

  // Wave 0: suffix scan -> largest cut with count(bin>=cut) >= K.
  if (t < 64 && K > 0) {
    unsigned s = 0;
    for (int b = 0; b < 64; ++b) s += u.tk.hist[t * 64 + b];
    unsigned suf = s;
    for (int d = 1; d < 64; d <<= 1) {
      unsigned o = __shfl_down(suf, d);
      if (t + d < 64) suf += o;
    }
    unsigned long long m1 = __ballot(suf >= (unsigned)K);
    int S = 63 - __builtin_clzll(m1);
    unsigned tail = 0;
    if (S < 63) tail = __shfl(suf, S + 1);
    unsigned suf2 = u.tk.hist[S * 64 + t];
    for (int d = 1; d < 64; d <<= 1) {
      unsigned o = __shfl_down(suf2, d);
      if (t + d < 64) suf2 += o;
    }
    unsigned long long m2 = __ballot((suf2 + tail) >= (unsigned)K);
    int Ls = 63 - __builtin_clzll(m2);
    if (t == 0) s_cut = S * 64 + Ls;
  }
  __syncthreads();
  const int cut = s_cut;

  // Prefill ranks >= K (reference: topv==0 -> box 0, score 0, label -1).
  for (int k = t; k < DETS; k += 256) {
    if (k >= K) {
      float* d = dets_out + (size_t)(img * DETS + k) * 5;
      d[0] = 0.0f; d[1] = 0.0f; d[2] = 0.0f; d[3] = 0.0f; d[4] = 0.0f;
      labels_out[img * DETS + k] = -1.0f;
    }
  }

  // Select bin >= cut: in-set rank == global rank (excluded strictly smaller).
  for (int i = t; i < n2; i += 256) {
    unsigned long long v = __hip_atomic_load(&cb[i], __ATOMIC_RELAXED,
                                             __HIP_MEMORY_SCOPE_AGENT);
    float sc = __uint_as_float((unsigned)v);
    int bin = (int)(sc * (float)NBINS);
    if (bin > NBINS - 1) bin = NBINS - 1;
    if (bin >= cut) {
      int p = atomicAdd(&s_m, 1);
      if (p < SELCAP) {
        u.tk.sel_s[p] = sc;
        u.tk.sel_f[p] = (int)(unsigned)(v >> 32);
      }
    }
  }
  __syncthreads();
  const int m = s_m;

  if (m <= SELCAP) {
    for (int i = t; i < m; i += 256) {
      float si = u.tk.sel_s[i];
      int   fi = u.tk.sel_f[i];
      int rank = 0;
      for (int j = 0; j < m; ++j) {
        float sj = u.tk.sel_s[j];
        rank += (int)((sj > si) | ((sj == si) & (u.tk.sel_f[j] < fi)));
      }
      if (rank < DETS) {
        int c2 = fi / NN;
        int row = img * NN + (fi - c2 * NN);
        float x1 = props[row * 4 + 0], y1 = props[row * 4 + 1];
        float x2 = props[row * 4 + 2], y2 = props[row * 4 + 3];
        float w = x2 - x1 + 1.0f, h = y2 - y1 + 1.0f;
        float cx = x1 + 0.5f * w,  cy = y1 + 0.5f * h;
        const float* rg = reg + (size_t)row * (CC * 4) + (c2 + 1) * 4;
        float dx = rg[0] / 10.0f, dy = rg[1] / 10.0f;
        float dw = fminf(rg[2] / 5.0f, DW_CLIP);
        float dh = fminf(rg[3] / 5.0f, DW_CLIP);
        float pcx = dx * w + cx, pcy = dy * h + cy;
        float pw = expf(dw) * w, ph = expf(dh) * h;
        float* d = dets_out + (size_t)(img * DETS + rank) * 5;
        d[0] = fminf(fmaxf(pcx - 0.5f * pw, 0.0f), IMG_W_M1);
        d[1] = fminf(fmaxf(pcy - 0.5f * ph, 0.0f), IMG_H_M1);
        d[2] = fminf(fmaxf(pcx + 0.5f * pw - 1.0f, 0.0f), IMG_W_M1);
        d[3] = fminf(fmaxf(pcy + 0.5f * ph - 1.0f, 0.0f), IMG_H_M1);
        d[4] = si;
        labels_out[img * DETS + rank] = (float)(c2 + 1);
      }
    }
  } else {
    // Mass-tie fallback (never taken): exact O(n^2) rank via global reads.
    for (int i = t; i < n2; i += 256) {
      unsigned long long vi = __hip_atomic_load(&cb[i], __ATOMIC_RELAXED,
                                                __HIP_MEMORY_SCOPE_AGENT);
      float si = __uint_as_float((unsigned)vi);
      int   fi = (int)(unsigned)(vi >> 32);
      int rank = 0;
      for (int j = 0; j < n2; ++j) {
        unsigned long long vj = __hip_atomic_load(&cb[j], __ATOMIC_RELAXED,
                                                  __HIP_MEMORY_SCOPE_AGENT);
        float sj = __uint_as_float((unsigned)vj);
        int   fj = (int)(unsigned)(vj >> 32);
        rank += (int)((sj > si) | ((sj == si) & (fj < fi)));
      }
      if (rank < DETS) {
        int c2 = fi / NN;
        int row = img * NN + (fi - c2 * NN);
        float x1 = props[row * 4 + 0], y1 = props[row * 4 + 1];
        float x2 = props[row * 4 + 2], y2 = props[row * 4 + 3];
        float w = x2 - x1 + 1.0f, h = y2 - y1 + 1.0f;
        float cx = x1 + 0.5f * w,  cy = y1 + 0.5f * h;
        const float* rg = reg + (size_t)row * (CC * 4) + (c2 + 1) * 4;
        float dx = rg[0] / 10.0f, dy = rg[1] / 10.0f;
        float dw = fminf(rg[2] / 5.0f, DW_CLIP);
        float dh = fminf(rg[3] / 5.0f, DW_CLIP);
        float pcx = dx * w + cx, pcy = dy * h + cy;
        float pw = expf(dw) * w, ph = expf(dh) * h;
        float* d = dets_out + (size_t)(img * DETS + rank) * 5;
        d[0] = fminf(fmaxf(pcx - 0.5f * pw, 0.0f), IMG_W_M1);
        d[1] = fminf(fmaxf(pcy - 0.5f * ph, 0.0f), IMG_H_M1);
        d[2] = fminf(fmaxf(pcx + 0.5f * pw - 1.0f, 0.0f), IMG_W_M1);
        d[3] = fminf(fmaxf(pcy + 0.5f * ph - 1.0f, 0.0f), IMG_H_M1);
        d[4] = si;
        labels_out[img * DETS + rank] = (float)(c2 + 1);
      }
    }
  }
}

extern "C" void kernel_launch(void* const* d_in, const int* in_sizes, int n_in,
                              void* d_out, int out_size, void* d_ws, size_t ws_size,
                              hipStream_t stream) {
  const float* logits = (const float*)d_in[0];   // [8000, 81]
  const float* reg    = (const float*)d_in[1];   // [8000, 324]
  const float* props  = (const float*)d_in[2];   // [8000, 4]
  // d_in[3] = features, unused (OUTPUT_FEATURE=False)

  float* out = (float*)d_out;                    // dets [8,100,5] then labels [8,100]
  char* ws = (char*)d_ws;
  unsigned long long* cand     = (unsigned long long*)(ws);
  unsigned*           counters = (unsigned*)(ws + 5120000);
  unsigned*           done     = (unsigned*)(ws + 5120064);

  fused_post<<<BB * NC, 256, 0, stream>>>(logits, reg, props, cand, counters,
                                          done, out, out + BB * DETS * 5);
}

// Round 8
// 157.056 us; speedup vs baseline: 15.1237x; 1.9212x over previous
//
#include <hip/hip_runtime.h>
#include <math.h>

#define BB 8
#define NN 1000
#define CC 81
#define NC 80                     // foreground classes
#define IMG_W_M1 1332.0f
#define IMG_H_M1 799.0f
#define SCORE_THRESH 0.05f
#define NMS_THRESH 0.5f
#define DETS 100
#define DW_CLIP 4.135166556742356f  // log(1000/16) rounded to f32
#define NBINS 4096
#define SELCAP 1024
#define CAPI 80000                // per-image survivor cap = 80*1000 absolute max
#define RPB 64                    // rows per block in row_stats

// ws layout (bytes):
//   [0,        5120000)  cand u64[8][CAPI] = {hi: flatidx, lo: score bits}
//   [5120000,  5120032)  counters u32[8]   (survivor count per image)
//   [5120064,  5120096)  done     u32[8]   (finished-block count per image)
//   [5120128,  5152128)  m_glob  f32[8000]
//   [5152128,  5184128)  s_glob  f32[8000]

__global__ __launch_bounds__(64) void row_stats(
    const float* __restrict__ logits, float* __restrict__ m_glob,
    float* __restrict__ s_glob, unsigned* __restrict__ counters) {
#pragma clang fp contract(off)
  __shared__ float s_l[RPB * CC];          // 20736 B
  const int b = blockIdx.x;
  const int t = threadIdx.x;
  if (b == 0 && t < 16) counters[t < 8 ? t : 16 + (t - 8)] = 0u;  // counters[0..7], done[0..7]

  // Coalesced staging: this block's 64 rows are 5184 contiguous floats.
  const float4* src = (const float4*)(logits + (size_t)b * RPB * CC);
  float4* dst = (float4*)s_l;
  for (int i = t; i < RPB * CC / 4; i += 64) dst[i] = src[i];
  __syncthreads();

  const int r = b * RPB + t;               // 125*64 == 8000 exactly
  const float* l = s_l + t * CC;           // stride 81: 2 lanes/bank -> free
  float m = l[0];
  for (int c = 1; c < CC; ++c) m = fmaxf(m, l[c]);
  float s = 0.0f;
  for (int c = 0; c < CC; ++c) s += expf(l[c] - m);
  m_glob[r] = m;                           // coalesced
  s_glob[r] = s;
}

__device__ __forceinline__ void emit_cand(unsigned long long* cand, int img,
                                          int pos, float sc, int fl) {
  if (pos >= 0 && pos < CAPI) {
    unsigned long long v = ((unsigned long long)(unsigned)fl << 32) |
                           (unsigned long long)__float_as_uint(sc);
    __hip_atomic_store(&cand[(size_t)img * CAPI + pos], v,
                       __ATOMIC_RELAXED, __HIP_MEMORY_SCOPE_AGENT);
  }
}

__global__ __launch_bounds__(256) void fused_nms_topk(
    const float* __restrict__ logits, const float* __restrict__ reg,
    const float* __restrict__ props, const float* __restrict__ m_glob,
    const float* __restrict__ s_glob, unsigned long long* __restrict__ cand,
    unsigned* __restrict__ counters, unsigned* __restrict__ done,
    float* __restrict__ dets_out, float* __restrict__ labels_out) {
#pragma clang fp contract(off)
  __shared__ float m_row[NN];
  __shared__ float s_row[NN];
  __shared__ union {
    struct {
      float score[NN]; int idx[NN];
      float sscore[NN]; int sidx[NN];
      float bx1[NN], by1[NN], bx2[NN], by2[NN];  // stride-1: no bank conflicts
      unsigned char keep[NN];
    } nms;                                   // 33 KB
    struct {
      unsigned hist[NBINS];                  // 16 KB
      float sel_s[SELCAP]; int sel_f[SELCAP];
    } tk;
  } u;
  __shared__ int s_cnt;
  __shared__ unsigned s_base;
  __shared__ int s_last, s_n2, s_m, s_cut;

  const int img = blockIdx.x / NC;
  const int cm1 = blockIdx.x % NC;
  const int cls = cm1 + 1;
  const int t = threadIdx.x;

  if (t == 0) s_cnt = 0;
  // Stage precomputed stats (coalesced, 8 KB)
  for (int r = t; r < NN; r += 256) {
    m_row[r] = m_glob[img * NN + r];
    s_row[r] = s_glob[img * NN + r];
  }
  __syncthreads();

  // ---- Phase 1: threshold + compact (prob formula verified R6/R7) ----
  for (int r = t; r < NN; r += 256) {
    float lc = logits[(size_t)(img * NN + r) * CC + cls];
    float p = expf(lc - m_row[r]) / s_row[r];
    if (p > SCORE_THRESH) {
      int pos = atomicAdd(&s_cnt, 1);
      u.nms.score[pos] = p;
      u.nms.idx[pos] = r;
    }
  }
  __syncthreads();
  const int n = s_cnt;

  // ---- Phase 2: rank sort by (score desc, row asc) == stable argsort ----
  for (int i = t; i < n; i += 256) {
    float si = u.nms.score[i];
    int   ii = u.nms.idx[i];
    int rank = 0;
    for (int j = 0; j < n; ++j) {
      float sj = u.nms.score[j];
      rank += (int)((sj > si) | ((sj == si) & (u.nms.idx[j] < ii)));
    }
    u.nms.sscore[rank] = si;
    u.nms.sidx[rank] = ii;
  }
  __syncthreads();

  // ---- Phase 3: decode + clip (BoxCoder.decode, TO_REMOVE=1; verbatim) ----
  for (int i = t; i < n; i += 256) {
    int r = u.nms.sidx[i];
    int row = img * NN + r;
    float x1 = props[row * 4 + 0], y1 = props[row * 4 + 1];
    float x2 = props[row * 4 + 2], y2 = props[row * 4 + 3];
    float w = x2 - x1 + 1.0f, h = y2 - y1 + 1.0f;
    float cx = x1 + 0.5f * w,  cy = y1 + 0.5f * h;
    const float* rg = reg + (size_t)row * (CC * 4) + cls * 4;
    float dx = rg[0] / 10.0f, dy = rg[1] / 10.0f;
    float dw = fminf(rg[2] / 5.0f, DW_CLIP);
    float dh = fminf(rg[3] / 5.0f, DW_CLIP);
    float pcx = dx * w + cx, pcy = dy * h + cy;
    float pw = expf(dw) * w, ph = expf(dh) * h;
    u.nms.bx1[i] = fminf(fmaxf(pcx - 0.5f * pw, 0.0f), IMG_W_M1);
    u.nms.by1[i] = fminf(fmaxf(pcy - 0.5f * ph, 0.0f), IMG_H_M1);
    u.nms.bx2[i] = fminf(fmaxf(pcx + 0.5f * pw - 1.0f, 0.0f), IMG_W_M1);
    u.nms.by2[i] = fminf(fmaxf(pcy + 0.5f * ph - 1.0f, 0.0f), IMG_H_M1);
    u.nms.keep[i] = 1;
  }
  __syncthreads();

  // ---- Phase 4+5: greedy NMS + emit survivors (verified R5/R7 logic) ----
  if (n <= 64) {
    if (t < 64) {
      bool own = t < n;
      float bx1 = 0.f, by1 = 0.f, bx2 = 0.f, by2 = 0.f;
      if (own) {
        bx1 = u.nms.bx1[t]; by1 = u.nms.by1[t];
        bx2 = u.nms.bx2[t]; by2 = u.nms.by2[t];
      }
      float areaSelf = (bx2 - bx1) * (by2 - by1);
      unsigned long long rem = __ballot(own);
      unsigned long long kept = 0ull;
      while (rem) {
        int i = __builtin_ctzll(rem);
        kept |= 1ull << i;
        rem &= ~(1ull << i);
        float cx1 = __shfl(bx1, i), cy1 = __shfl(by1, i);
        float cx2 = __shfl(bx2, i), cy2 = __shfl(by2, i);
        float areaB = (cx2 - cx1) * (cy2 - cy1);
        float wx = fmaxf(fminf(bx2, cx2) - fmaxf(bx1, cx1), 0.0f);
        float wy = fmaxf(fminf(by2, cy2) - fmaxf(by1, cy1), 0.0f);
        float inter = wx * wy;
        float iou = inter / ((areaSelf + areaB) - inter + 1e-9f);
        rem &= ~__ballot(iou > NMS_THRESH);
      }
      int tot = (int)__popcll(kept);
      unsigned base = 0u;
      if (t == 0 && tot > 0) base = atomicAdd(&counters[img], (unsigned)tot);
      base = __shfl(base, 0);
      if (own && ((kept >> t) & 1ull)) {
        int pos = (int)base + (int)__popcll(kept & ((1ull << t) - 1ull));
        emit_cand(cand, img, pos, u.nms.sscore[t], cm1 * NN + u.nms.sidx[t]);
      }
    }
  } else {
    // Generic fallback (n>64): barriered LDS loop, identical semantics.
    for (int i = 0; i < n; ++i) {
      if (u.nms.keep[i]) {
        float ax1 = u.nms.bx1[i], ay1 = u.nms.by1[i];
        float ax2 = u.nms.bx2[i], ay2 = u.nms.by2[i];
        float areaA = (ax2 - ax1) * (ay2 - ay1);
        for (int j = i + 1 + t; j < n; j += 256) {
          if (!u.nms.keep[j]) continue;
          float bx1 = u.nms.bx1[j], by1 = u.nms.by1[j];
          float bx2 = u.nms.bx2[j], by2 = u.nms.by2[j];
          float areaB = (bx2 - bx1) * (by2 - by1);
          float wx = fmaxf(fminf(ax2, bx2) - fmaxf(ax1, bx1), 0.0f);
          float wy = fmaxf(fminf(ay2, by2) - fmaxf(ay1, by1), 0.0f);
          float inter = wx * wy;
          if (inter / ((areaA + areaB) - inter + 1e-9f) > NMS_THRESH)
            u.nms.keep[j] = 0;
        }
      }
      __syncthreads();
    }
    if (t == 0) {
      int tot = 0;
      for (int j = 0; j < n; ++j) tot += (int)u.nms.keep[j];
      s_base = (tot > 0) ? atomicAdd(&counters[img], (unsigned)tot) : 0u;
    }
    __syncthreads();
    for (int i = t; i < n; i += 256) {
      if (u.nms.keep[i]) {
        int pos = 0;
        for (int j = 0; j < i; ++j) pos += (int)u.nms.keep[j];
        emit_cand(cand, img, (int)s_base + pos,
                  u.nms.sscore[i], cm1 * NN + u.nms.sidx[i]);
      }
    }
  }

  // ---- Signal done; last block of the image runs topk (verified R7) ----
  __threadfence();
  __syncthreads();
  if (t == 0) {
    unsigned old = __hip_atomic_fetch_add(&done[img], 1u,
                                          __ATOMIC_ACQ_REL,
                                          __HIP_MEMORY_SCOPE_AGENT);
    s_last = (old == NC - 1) ? 1 : 0;
  }
  __syncthreads();
  if (!s_last) return;

  __threadfence();
  if (t == 0) {
    s_n2 = (int)__hip_atomic_load(&counters[img], __ATOMIC_ACQUIRE,
                                  __HIP_MEMORY_SCOPE_AGENT);
    s_m = 0; s_cut = NBINS;
  }
  __syncthreads();
  for (int b = t; b < NBINS; b += 256) u.tk.hist[b] = 0u;
  __syncthreads();

  int n2 = s_n2;
  if (n2 > CAPI) n2 = CAPI;
  const int K = (n2 < DETS) ? n2 : DETS;
  const unsigned long long* cb = cand + (size_t)img * CAPI;

  for (int i = t; i < n2; i += 256) {
    unsigned long long v = __hip_atomic_load(&cb[i], __ATOMIC_RELAXED,
                                             __HIP_MEMORY_SCOPE_AGENT);
    float sc = __uint_as_float((unsigned)v);
    int bin = (int)(sc * (float)NBINS);
    if (bin > NBINS - 1) bin = NBINS - 1;
    atomicAdd(&u.tk.hist[bin], 1u);
  }
  __syncthreads();

  if (t < 64 && K > 0) {
    unsigned s = 0;
    for (int b = 0; b < 64; ++b) s += u.tk.hist[t * 64 + b];
    unsigned suf = s;
    for (int d = 1; d < 64; d <<= 1) {
      unsigned o = __shfl_down(suf, d);
      if (t + d < 64) suf += o;
    }
    unsigned long long m1 = __ballot(suf >= (unsigned)K);
    int S = 63 - __builtin_clzll(m1);
    unsigned tail = 0;
    if (S < 63) tail = __shfl(suf, S + 1);
    unsigned suf2 = u.tk.hist[S * 64 + t];
    for (int d = 1; d < 64; d <<= 1) {
      unsigned o = __shfl_down(suf2, d);
      if (t + d < 64) suf2 += o;
    }
    unsigned long long m2 = __ballot((suf2 + tail) >= (unsigned)K);
    int Ls = 63 - __builtin_clzll(m2);
    if (t == 0) s_cut = S * 64 + Ls;
  }
  __syncthreads();
  const int cut = s_cut;

  for (int k = t; k < DETS; k += 256) {
    if (k >= K) {
      float* d = dets_out + (size_t)(img * DETS + k) * 5;
      d[0] = 0.0f; d[1] = 0.0f; d[2] = 0.0f; d[3] = 0.0f; d[4] = 0.0f;
      labels_out[img * DETS + k] = -1.0f;
    }
  }

  for (int i = t; i < n2; i += 256) {
    unsigned long long v = __hip_atomic_load(&cb[i], __ATOMIC_RELAXED,
                                             __HIP_MEMORY_SCOPE_AGENT);
    float sc = __uint_as_float((unsigned)v);
    int bin = (int)(sc * (float)NBINS);
    if (bin > NBINS - 1) bin = NBINS - 1;
    if (bin >= cut) {
      int p = atomicAdd(&s_m, 1);
      if (p < SELCAP) {
        u.tk.sel_s[p] = sc;
        u.tk.sel_f[p] = (int)(unsigned)(v >> 32);
      }
    }
  }
  __syncthreads();
  const int m = s_m;

  if (m <= SELCAP) {
    for (int i = t; i < m; i += 256) {
      float si = u.tk.sel_s[i];
      int   fi = u.tk.sel_f[i];
      int rank = 0;
      for (int j = 0; j < m; ++j) {
        float sj = u.tk.sel_s[j];
        rank += (int)((sj > si) | ((sj == si) & (u.tk.sel_f[j] < fi)));
      }
      if (rank < DETS) {
        int c2 = fi / NN;
        int row = img * NN + (fi - c2 * NN);
        float x1 = props[row * 4 + 0], y1 = props[row * 4 + 1];
        float x2 = props[row * 4 + 2], y2 = props[row * 4 + 3];
        float w = x2 - x1 + 1.0f, h = y2 - y1 + 1.0f;
        float cx = x1 + 0.5f * w,  cy = y1 + 0.5f * h;
        const float* rg = reg + (size_t)row * (CC * 4) + (c2 + 1) * 4;
        float dx = rg[0] / 10.0f, dy = rg[1] / 10.0f;
        float dw = fminf(rg[2] / 5.0f, DW_CLIP);
        float dh = fminf(rg[3] / 5.0f, DW_CLIP);
        float pcx = dx * w + cx, pcy = dy * h + cy;
        float pw = expf(dw) * w, ph = expf(dh) * h;
        float* d = dets_out + (size_t)(img * DETS + rank) * 5;
        d[0] = fminf(fmaxf(pcx - 0.5f * pw, 0.0f), IMG_W_M1);
        d[1] = fminf(fmaxf(pcy - 0.5f * ph, 0.0f), IMG_H_M1);
        d[2] = fminf(fmaxf(pcx + 0.5f * pw - 1.0f, 0.0f), IMG_W_M1);
        d[3] = fminf(fmaxf(pcy + 0.5f * ph - 1.0f, 0.0f), IMG_H_M1);
        d[4] = si;
        labels_out[img * DETS + rank] = (float)(c2 + 1);
      }
    }
  } else {
    // Mass-tie fallback (never taken): exact O(n^2) rank via global reads.
    for (int i = t; i < n2; i += 256) {
      unsigned long long vi = __hip_atomic_load(&cb[i], __ATOMIC_RELAXED,
                                                __HIP_MEMORY_SCOPE_AGENT);
      float si = __uint_as_float((unsigned)vi);
      int   fi = (int)(unsigned)(vi >> 32);
      int rank = 0;
      for (int j = 0; j < n2; ++j) {
        unsigned long long vj = __hip_atomic_load(&cb[j], __ATOMIC_RELAXED,
                                                  __HIP_MEMORY_SCOPE_AGENT);
        float sj = __uint_as_float((unsigned)vj);
        int   fj = (int)(unsigned)(vj >> 32);
        rank += (int)((sj > si) | ((sj == si) & (fj < fi)));
      }
      if (rank < DETS) {
        int c2 = fi / NN;
        int row = img * NN + (fi - c2 * NN);
        float x1 = props[row * 4 + 0], y1 = props[row * 4 + 1];
        float x2 = props[row * 4 + 2], y2 = props[row * 4 + 3];
        float w = x2 - x1 + 1.0f, h = y2 - y1 + 1.0f;
        float cx = x1 + 0.5f * w,  cy = y1 + 0.5f * h;
        const float* rg = reg + (size_t)row * (CC * 4) + (c2 + 1) * 4;
        float dx = rg[0] / 10.0f, dy = rg[1] / 10.0f;
        float dw = fminf(rg[2] / 5.0f, DW_CLIP);
        float dh = fminf(rg[3] / 5.0f, DW_CLIP);
        float pcx = dx * w + cx, pcy = dy * h + cy;
        float pw = expf(dw) * w, ph = expf(dh) * h;
        float* d = dets_out + (size_t)(img * DETS + rank) * 5;
        d[0] = fminf(fmaxf(pcx - 0.5f * pw, 0.0f), IMG_W_M1);
        d[1] = fminf(fmaxf(pcy - 0.5f * ph, 0.0f), IMG_H_M1);
        d[2] = fminf(fmaxf(pcx + 0.5f * pw - 1.0f, 0.0f), IMG_W_M1);
        d[3] = fminf(fmaxf(pcy + 0.5f * ph - 1.0f, 0.0f), IMG_H_M1);
        d[4] = si;
        labels_out[img * DETS + rank] = (float)(c2 + 1);
      }
    }
  }
}

extern "C" void kernel_launch(void* const* d_in, const int* in_sizes, int n_in,
                              void* d_out, int out_size, void* d_ws, size_t ws_size,
                              hipStream_t stream) {
  const float* logits = (const float*)d_in[0];   // [8000, 81]
  const float* reg    = (const float*)d_in[1];   // [8000, 324]
  const float* props  = (const float*)d_in[2];   // [8000, 4]
  // d_in[3] = features, unused (OUTPUT_FEATURE=False)

  float* out = (float*)d_out;                    // dets [8,100,5] then labels [8,100]
  char* ws = (char*)d_ws;
  unsigned long long* cand     = (unsigned long long*)(ws);
  unsigned*           counters = (unsigned*)(ws + 5120000);  // done at +5120064 = counters+16
  unsigned*           done     = (unsigned*)(ws + 5120064);
  float*              m_glob   = (float*)(ws + 5120128);
  float*              s_glob   = (float*)(ws + 5152128);

  row_stats<<<BB * NN / RPB, 64, 0, stream>>>(logits, m_glob, s_glob, counters);
  fused_nms_topk<<<BB * NC, 256, 0, stream>>>(logits, reg, props, m_glob, s_glob,
                                              cand, counters, done,
                                              out, out + BB * DETS * 5);
}